// Round 1
// baseline (1788.364 us; speedup 1.0000x reference)
//
#include <hip/hip_runtime.h>
#include <hip/hip_bf16.h>

#define N_NODES 12500
#define N_EDGES 400000
#define N_RADIAL 128
#define HIDDEN 64
#define WIG_LD 19
#define WIG_ROW 475   // 25*19
#define OUTF 1600     // 25*64
#define FULL 25

typedef __attribute__((ext_vector_type(8))) __bf16 bf16x8;
typedef __attribute__((ext_vector_type(4))) float f32x4;

// ---- workspace layout (bytes) ----
#define W1DT_OFF 0         // bf16 [64][128]   = 16384
#define W2T_OFF  16384     // bf16 [64][64]    = 8192
#define W3T_OFF  24576     // bf16 [320][64]   = 40960
#define S1_OFF   65536     // f32  [90][64]    = 23040
#define R1_OFF   90112     // f32  [90][64]    = 23040
#define CNT_OFF  114688    // int  [12500]
#define OFFS_OFF 167936    // int  [12501]
#define CURS_OFF 221184    // int  [12500]
#define EIDS_OFF 274432    // int  [400000]  -> ends ~1.87 MB

// ============ prep: weight transposes (bf16) + species tables ============
__global__ void prep_k(const float* __restrict__ W1, const float* __restrict__ W2,
                       const float* __restrict__ W3,
                       const float* __restrict__ send_emb, const float* __restrict__ recv_emb,
                       __bf16* __restrict__ W1dT, __bf16* __restrict__ W2T,
                       __bf16* __restrict__ W3T, float* __restrict__ S1, float* __restrict__ R1) {
    int t = blockIdx.x * 256 + threadIdx.x;
    if (t < 8192) {                     // W1dT[n][k] = W1[k][n], k<128
        int n = t >> 7, k = t & 127;
        W1dT[t] = (__bf16)W1[k * 64 + n];
    } else if (t < 12288) {             // W2T[n][k] = W2[k][n]
        int i = t - 8192; int n = i >> 6, k = i & 63;
        W2T[i] = (__bf16)W2[k * 64 + n];
    } else if (t < 32768) {             // W3T[n][k] = W3[k][n], n<320
        int i = t - 12288; int n = i >> 6, k = i & 63;
        W3T[i] = (__bf16)W3[k * 320 + n];
    } else if (t < 38528) {             // S1[sp][h] = send_emb[sp]·W1[128:192, h]
        int i = t - 32768; int sp = i >> 6, h = i & 63;
        float s = 0.f;
        for (int j = 0; j < 64; j++) s += send_emb[sp * 64 + j] * W1[(128 + j) * 64 + h];
        S1[i] = s;
    } else if (t < 44288) {             // R1[sp][h] = recv_emb[sp]·W1[192:256, h]
        int i = t - 38528; int sp = i >> 6, h = i & 63;
        float s = 0.f;
        for (int j = 0; j < 64; j++) s += recv_emb[sp * 64 + j] * W1[(192 + j) * 64 + h];
        R1[i] = s;
    }
}

// ============ CSR build ============
__global__ void hist_k(const int* __restrict__ recv, int* __restrict__ cnt) {
    int e = blockIdx.x * 256 + threadIdx.x;
    if (e < N_EDGES) atomicAdd(&cnt[recv[e]], 1);
}

__global__ void scan_k(const int* __restrict__ cnt, int* __restrict__ offs,
                       int* __restrict__ cursor) {
    __shared__ int part[256];
    int t = threadIdx.x;
    const int CH = 49; // 256*49 >= 12500
    int base = t * CH;
    int s = 0;
    for (int i = 0; i < CH; i++) { int idx = base + i; if (idx < N_NODES) s += cnt[idx]; }
    part[t] = s;
    __syncthreads();
    for (int off = 1; off < 256; off <<= 1) {
        int add = (t >= off) ? part[t - off] : 0;
        __syncthreads();
        part[t] += add;
        __syncthreads();
    }
    int prefix = (t > 0) ? part[t - 1] : 0;
    for (int i = 0; i < CH; i++) {
        int idx = base + i;
        if (idx < N_NODES) { offs[idx] = prefix; cursor[idx] = prefix; prefix += cnt[idx]; }
    }
    if (t == 0) offs[N_NODES] = part[255];
}

__global__ void scat_k(const int* __restrict__ recv, int* __restrict__ cursor,
                       int* __restrict__ eids) {
    int e = blockIdx.x * 256 + threadIdx.x;
    if (e < N_EDGES) {
        int p = atomicAdd(&cursor[recv[e]], 1);
        eids[p] = e;
    }
}

// ============ main fused node-centric kernel ============
// block = 256 threads = 4 waves; one block per node.
// MLP phase: wave w runs 3-layer MFMA MLP for 16-edge tile (tb+w), result g -> sG.
// Wigner phase: node[f,c] += wig^T @ g as MFMA GEMM over K = (edge,m); wave w owns c-block w.
__global__ __launch_bounds__(256, 2) void edeg_main(
    const int* __restrict__ species, const float* __restrict__ dist,
    const int* __restrict__ senders, const int* __restrict__ receivers,
    const float* __restrict__ wig, const float* __restrict__ env,
    const float* __restrict__ b1, const float* __restrict__ g1, const float* __restrict__ be1,
    const float* __restrict__ b2, const float* __restrict__ g2, const float* __restrict__ be2,
    const float* __restrict__ b3,
    const __bf16* __restrict__ W1dT, const __bf16* __restrict__ W2T,
    const __bf16* __restrict__ W3T,
    const float* __restrict__ S1, const float* __restrict__ R1,
    const int* __restrict__ cnt, const int* __restrict__ offs, const int* __restrict__ eids,
    float* __restrict__ out) {
    __shared__ __align__(16) __bf16 sG[64][320];   // g for up to 4 tiles of 16 edges
    __shared__ __align__(16) __bf16 sT[4][16][72]; // per-wave transpose buffer (+8 pad)
    __shared__ int sEid[64];

    const int n = blockIdx.x;
    const int count = cnt[n];
    const int start = offs[n];
    const int t = threadIdx.x;
    const int w = t >> 6;       // wave id
    const int l = t & 63;       // lane
    const int lo = l & 15;
    const int q = l >> 4;       // quad
    const int cc = w * 16 + lo; // this wave's output column
    const int ntiles = (count + 15) >> 4;

    f32x4 Cw0 = {0.f, 0.f, 0.f, 0.f};
    f32x4 Cw1 = {0.f, 0.f, 0.f, 0.f};

    for (int tb = 0; tb < ntiles; tb += 4) {
        if (tb) __syncthreads();
        const int myt = tb + w;
        if (myt < ntiles) {
            // ---- edge ids for this tile (pad with first edge; masked by scl=0) ----
            if (l < 16) {
                int idx = myt * 16 + l;
                sEid[w * 16 + l] = eids[start + (idx < count ? idx : 0)];
            }
            const int eA = sEid[w * 16 + lo]; // same-wave LDS RAW: in-order, safe

            // ---- layer 1: [16x128] @ [128x64] ----
            const float* drow = dist + (size_t)eA * N_RADIAL;
            bf16x8 A1[4];
#pragma unroll
            for (int kk = 0; kk < 4; kk++) {
                const float4* dp = (const float4*)(drow + kk * 32 + q * 8);
                float4 x = dp[0], y = dp[1];
                bf16x8 a;
                a[0] = (__bf16)x.x; a[1] = (__bf16)x.y; a[2] = (__bf16)x.z; a[3] = (__bf16)x.w;
                a[4] = (__bf16)y.x; a[5] = (__bf16)y.y; a[6] = (__bf16)y.z; a[7] = (__bf16)y.w;
                A1[kk] = a;
            }
            f32x4 C1[4];
#pragma unroll
            for (int nt = 0; nt < 4; nt++) {
                f32x4 c = {0.f, 0.f, 0.f, 0.f};
#pragma unroll
                for (int kk = 0; kk < 4; kk++) {
                    bf16x8 B = *(const bf16x8*)(W1dT + (nt * 16 + lo) * 128 + kk * 32 + q * 8);
                    c = __builtin_amdgcn_mfma_f32_16x16x32_bf16(A1[kk], B, c, 0, 0, 0);
                }
                C1[nt] = c;
            }
            // ---- epilogue 1: + b1 + S1[sp_s] + R1[sp_r], LN, SiLU ----
            int e_r[4], sps[4], spr[4];
#pragma unroll
            for (int r = 0; r < 4; r++) {
                int e = sEid[w * 16 + q * 4 + r];
                e_r[r] = e;
                sps[r] = species[senders[e]];
                spr[r] = species[receivers[e]];
            }
            float v[4][4];
#pragma unroll
            for (int nt = 0; nt < 4; nt++) {
                int h = nt * 16 + lo;
                float bb = b1[h];
#pragma unroll
                for (int r = 0; r < 4; r++)
                    v[nt][r] = C1[nt][r] + bb + S1[sps[r] * 64 + h] + R1[spr[r] * 64 + h];
            }
            float mu[4], rstd[4];
#pragma unroll
            for (int r = 0; r < 4; r++) {
                float s = v[0][r] + v[1][r] + v[2][r] + v[3][r];
                s += __shfl_xor(s, 1); s += __shfl_xor(s, 2);
                s += __shfl_xor(s, 4); s += __shfl_xor(s, 8);
                mu[r] = s * (1.f / 64.f);
            }
#pragma unroll
            for (int r = 0; r < 4; r++) {
                float s = 0.f;
#pragma unroll
                for (int nt = 0; nt < 4; nt++) { float d = v[nt][r] - mu[r]; s += d * d; }
                s += __shfl_xor(s, 1); s += __shfl_xor(s, 2);
                s += __shfl_xor(s, 4); s += __shfl_xor(s, 8);
                rstd[r] = rsqrtf(s * (1.f / 64.f) + 1e-5f);
            }
#pragma unroll
            for (int nt = 0; nt < 4; nt++) {
                int h = nt * 16 + lo;
                float gg = g1[h], bb = be1[h];
#pragma unroll
                for (int r = 0; r < 4; r++) {
                    float x = (v[nt][r] - mu[r]) * rstd[r] * gg + bb;
                    x = x / (1.f + __expf(-x)); // SiLU
                    sT[w][q * 4 + r][h] = (__bf16)x;
                }
            }
            // ---- layer 2: [16x64] @ [64x64] ----
            bf16x8 A2[2];
#pragma unroll
            for (int kk = 0; kk < 2; kk++)
                A2[kk] = *(const bf16x8*)(&sT[w][lo][kk * 32 + q * 8]);
            f32x4 C2[4];
#pragma unroll
            for (int nt = 0; nt < 4; nt++) {
                f32x4 c = {0.f, 0.f, 0.f, 0.f};
#pragma unroll
                for (int kk = 0; kk < 2; kk++) {
                    bf16x8 B = *(const bf16x8*)(W2T + (nt * 16 + lo) * 64 + kk * 32 + q * 8);
                    c = __builtin_amdgcn_mfma_f32_16x16x32_bf16(A2[kk], B, c, 0, 0, 0);
                }
                C2[nt] = c;
            }
#pragma unroll
            for (int nt = 0; nt < 4; nt++) {
                int h = nt * 16 + lo;
                float bb = b2[h];
#pragma unroll
                for (int r = 0; r < 4; r++) v[nt][r] = C2[nt][r] + bb;
            }
#pragma unroll
            for (int r = 0; r < 4; r++) {
                float s = v[0][r] + v[1][r] + v[2][r] + v[3][r];
                s += __shfl_xor(s, 1); s += __shfl_xor(s, 2);
                s += __shfl_xor(s, 4); s += __shfl_xor(s, 8);
                mu[r] = s * (1.f / 64.f);
            }
#pragma unroll
            for (int r = 0; r < 4; r++) {
                float s = 0.f;
#pragma unroll
                for (int nt = 0; nt < 4; nt++) { float d = v[nt][r] - mu[r]; s += d * d; }
                s += __shfl_xor(s, 1); s += __shfl_xor(s, 2);
                s += __shfl_xor(s, 4); s += __shfl_xor(s, 8);
                rstd[r] = rsqrtf(s * (1.f / 64.f) + 1e-5f);
            }
#pragma unroll
            for (int nt = 0; nt < 4; nt++) {
                int h = nt * 16 + lo;
                float gg = g2[h], bb = be2[h];
#pragma unroll
                for (int r = 0; r < 4; r++) {
                    float x = (v[nt][r] - mu[r]) * rstd[r] * gg + bb;
                    x = x / (1.f + __expf(-x));
                    sT[w][q * 4 + r][h] = (__bf16)x;
                }
            }
            // ---- layer 3: [16x64] @ [64x320] ----
            bf16x8 A3[2];
#pragma unroll
            for (int kk = 0; kk < 2; kk++)
                A3[kk] = *(const bf16x8*)(&sT[w][lo][kk * 32 + q * 8]);
            f32x4 C3[20];
#pragma unroll
            for (int nt = 0; nt < 20; nt++) {
                f32x4 c = {0.f, 0.f, 0.f, 0.f};
#pragma unroll
                for (int kk = 0; kk < 2; kk++) {
                    bf16x8 B = *(const bf16x8*)(W3T + (nt * 16 + lo) * 64 + kk * 32 + q * 8);
                    c = __builtin_amdgcn_mfma_f32_16x16x32_bf16(A3[kk], B, c, 0, 0, 0);
                }
                C3[nt] = c;
            }
            // ---- epilogue 3: +b3, *env/RESCALE, -> sG (bf16) ----
            float scl[4];
#pragma unroll
            for (int r = 0; r < 4; r++) {
                int idx = myt * 16 + q * 4 + r;
                scl[r] = (idx < count) ? env[e_r[r]] * 0.2f : 0.f;
            }
#pragma unroll
            for (int nt = 0; nt < 20; nt++) {
                float bb = b3[nt * 16 + lo];
#pragma unroll
                for (int r = 0; r < 4; r++)
                    sG[w * 16 + q * 4 + r][nt * 16 + lo] = (__bf16)((C3[nt][r] + bb) * scl[r]);
            }
        } else {
            // idle wave: zero its sG region, fallback edge ids (read-safe)
            if (l < 16) sEid[w * 16 + l] = eids[start];
            float4* p = (float4*)(&sG[w * 16][0]);
            float4 z = make_float4(0.f, 0.f, 0.f, 0.f);
#pragma unroll
            for (int i = 0; i < 10; i++) p[l + i * 64] = z;
        }
        __syncthreads();
        // ---- Wigner + segment-sum as MFMA GEMM over K=(edge,m) ----
        const int ntc = (ntiles - tb) < 4 ? (ntiles - tb) : 4;
        const int kkmax = (ntc * 80 + 31) >> 5;
        for (int kk = 0; kk < kkmax; kk++) {
            const int kbase = kk * 32 + q * 8;
            int e_k[8], m_k[8], eid_k[8];
#pragma unroll
            for (int j = 0; j < 8; j++) {
                int k = kbase + j;
                int e = k / 5;
                e_k[j] = e;
                m_k[j] = k - e * 5;
                eid_k[j] = sEid[e];
            }
            bf16x8 Bf;
#pragma unroll
            for (int j = 0; j < 8; j++)
                Bf[j] = sG[e_k[j]][m_k[j] * 64 + cc];
#pragma unroll
            for (int mt = 0; mt < 2; mt++) {
                int f = mt * 16 + lo;
                if (f > 24) f = 24; // clamp: rows f>=25 unused, keep loads in-bounds
                bf16x8 Af;
#pragma unroll
                for (int j = 0; j < 8; j++)
                    Af[j] = (__bf16)wig[(size_t)eid_k[j] * WIG_ROW + f * WIG_LD + m_k[j]];
                if (mt == 0) Cw0 = __builtin_amdgcn_mfma_f32_16x16x32_bf16(Af, Bf, Cw0, 0, 0, 0);
                else         Cw1 = __builtin_amdgcn_mfma_f32_16x16x32_bf16(Af, Bf, Cw1, 0, 0, 0);
            }
        }
    }
    // ---- write node output (count==0 nodes write zeros) ----
#pragma unroll
    for (int mt = 0; mt < 2; mt++) {
        f32x4 C = mt ? Cw1 : Cw0;
#pragma unroll
        for (int r = 0; r < 4; r++) {
            int f = mt * 16 + q * 4 + r;
            if (f < FULL) out[(size_t)n * OUTF + f * 64 + cc] = C[r];
        }
    }
}

extern "C" void kernel_launch(void* const* d_in, const int* in_sizes, int n_in,
                              void* d_out, int out_size, void* d_ws, size_t ws_size,
                              hipStream_t stream) {
    const int*   species   = (const int*)d_in[0];
    const float* dist      = (const float*)d_in[1];
    const int*   senders   = (const int*)d_in[2];
    const int*   receivers = (const int*)d_in[3];
    const float* wig       = (const float*)d_in[4];
    const float* env       = (const float*)d_in[5];
    const float* send_emb  = (const float*)d_in[6];
    const float* recv_emb  = (const float*)d_in[7];
    const float* W1  = (const float*)d_in[8];
    const float* b1  = (const float*)d_in[9];
    const float* g1  = (const float*)d_in[10];
    const float* be1 = (const float*)d_in[11];
    const float* W2  = (const float*)d_in[12];
    const float* b2  = (const float*)d_in[13];
    const float* g2  = (const float*)d_in[14];
    const float* be2 = (const float*)d_in[15];
    const float* W3  = (const float*)d_in[16];
    const float* b3  = (const float*)d_in[17];

    char* ws = (char*)d_ws;
    __bf16* W1dT = (__bf16*)(ws + W1DT_OFF);
    __bf16* W2T  = (__bf16*)(ws + W2T_OFF);
    __bf16* W3T  = (__bf16*)(ws + W3T_OFF);
    float*  S1   = (float*)(ws + S1_OFF);
    float*  R1   = (float*)(ws + R1_OFF);
    int* cntp  = (int*)(ws + CNT_OFF);
    int* offsp = (int*)(ws + OFFS_OFF);
    int* cursp = (int*)(ws + CURS_OFF);
    int* eidsp = (int*)(ws + EIDS_OFF);

    hipMemsetAsync(cntp, 0, N_NODES * sizeof(int), stream);
    prep_k<<<173, 256, 0, stream>>>(W1, W2, W3, send_emb, recv_emb, W1dT, W2T, W3T, S1, R1);
    hist_k<<<(N_EDGES + 255) / 256, 256, 0, stream>>>(receivers, cntp);
    scan_k<<<1, 256, 0, stream>>>(cntp, offsp, cursp);
    scat_k<<<(N_EDGES + 255) / 256, 256, 0, stream>>>(receivers, cursp, eidsp);
    edeg_main<<<N_NODES, 256, 0, stream>>>(
        species, dist, senders, receivers, wig, env,
        b1, g1, be1, b2, g2, be2, b3,
        W1dT, W2T, W3T, S1, R1, cntp, offsp, eidsp, (float*)d_out);
}